// Round 2
// baseline (732.302 us; speedup 1.0000x reference)
//
#include <hip/hip_runtime.h>
#include <hip/hip_cooperative_groups.h>
#include <math.h>

namespace cg = cooperative_groups;

// Problem constants (from reference)
#define NN 100000          // nodes
#define LF 48              // features per node
#define NE 1600000         // edges
#define EDIMS 17           // edge_attr dim
#define MASKW 3125         // NN/32 bitmask words
#define CAP_E 16384        // per-level edge-list capacity (expected ~5k max level)
#define MAXLOC 12288       // active-node capacity (expected ~4.9k)
#define NBLK 256           // 1 block/CU -> cooperative co-residency guaranteed
#define NTHR 256
#define NT (NBLK * NTHR)
#define NWAVE (NT / 64)

static_assert(NN == MASKW * 32, "mask width");
static_assert((CAP_E & (CAP_E - 1)) == 0, "CAP_E pow2");

__device__ __forceinline__ float gelu_f(float x) {
    // jax.nn.gelu(approximate=False) = x * 0.5 * (1 + erf(x/sqrt(2)))
    return 0.5f * x * (1.0f + erff(x * 0.7071067811865475f));
}
__device__ __forceinline__ float sigm_f(float x) {
    return 1.0f / (1.0f + expf(-x));
}

// One fused cooperative kernel: BFS (3 levels) + compaction + edge-MLP (w0) +
// 3 gather/scatter iterations + output. All phases separated by grid.sync().
__global__ __launch_bounds__(NTHR, 2) void fused_gat(
    const float* __restrict__ nodes, const int* __restrict__ src, const int* __restrict__ dst,
    const float* __restrict__ eattr, const float* __restrict__ valid,
    const float* __restrict__ W1, const float* __restrict__ b1,
    const float* __restrict__ W2, const float* __restrict__ b2,
    const float* __restrict__ Wg, const float* __restrict__ bg,
    const float* __restrict__ Ww, const float* __restrict__ bw,
    const float* __restrict__ Wf, const float* __restrict__ bf,
    char* ws, float* __restrict__ out)
{
    cg::grid_group grid = cg::this_grid();
    const int tid  = blockIdx.x * NTHR + threadIdx.x;
    const int wave = tid >> 6;
    const int lane = tid & 63;

    // ---- workspace carve (256-aligned, compiler-foldable) ----
    size_t off = 0;
    auto carve = [&](size_t bytes) -> char* {
        char* p = ws + off;
        off += (bytes + 255) & ~(size_t)255;
        return p;
    };
    int*      counters = (int*)carve(64);              // [0]=|E3| [1]=|E2| [2]=|E1| [3]=nloc
    unsigned* M3 = (unsigned*)carve(MASKW * 4);        // S3 = {0}
    unsigned* M2 = (unsigned*)carve(MASKW * 4);        // S2 = S3 ∪ src(E3)
    unsigned* M1 = (unsigned*)carve(MASKW * 4);        // S1 = S2 ∪ src(E2)
    unsigned* M0 = (unsigned*)carve(MASKW * 4);        // S0 = S1 ∪ src(E1)
    int*      n2l = (int*)carve((size_t)NN * 4);       // only active entries ever read
    int*      l2n = (int*)carve((size_t)MAXLOC * 4);
    int4*     lists = (int4*)carve((size_t)3 * CAP_E * 16); // slot0=E3, slot1=E2, slot2=E1
    float*    X0 = (float*)carve((size_t)MAXLOC * LF * 4);  // original (and x_prev for iter 1)
    float*    XA = (float*)carve((size_t)MAXLOC * LF * 4);
    float*    XB = (float*)carve((size_t)MAXLOC * LF * 4);
    float*    VA = (float*)carve((size_t)MAXLOC * LF * 4);
    float*    VB = (float*)carve((size_t)MAXLOC * LF * 4);
    float*    MVA = (float*)carve((size_t)MAXLOC * 4);
    float*    MVB = (float*)carve((size_t)MAXLOC * 4);
    float*    agg = (float*)carve((size_t)MAXLOC * LF * 4);

    // ---- P0: zero + seed (node 0 is in every level set) ----
    for (int i = tid; i < 16; i += NT) counters[i] = 0;
    for (int i = tid; i < MASKW; i += NT) { M3[i] = 0u; M2[i] = 0u; M1[i] = 0u; M0[i] = 0u; }
    for (int i = tid; i < MAXLOC * LF; i += NT) agg[i] = 0.f;
    if (tid == 0) { M3[0] = 1u; M2[0] = 1u; M1[0] = 1u; M0[0] = 1u; }
    grid.sync();

    // ---- P1..P3: backward BFS, exact dst-sets per iteration ----
    {
        const unsigned* Mins[3]  = { M3, M2, M1 };
        unsigned*       Mouts[3] = { M2, M1, M0 };
        for (int lvl = 0; lvl < 3; ++lvl) {
            const unsigned* Min = Mins[lvl];
            unsigned* Mout = Mouts[lvl];
            int4* list = lists + lvl * CAP_E;
            int* cnt = counters + lvl;
            for (int e = tid; e < NE; e += NT) {
                int d = dst[e];
                if (Min[d >> 5] & (1u << (d & 31))) {
                    int s = src[e];
                    int idx = atomicAdd(cnt, 1);
                    if (idx < CAP_E) list[idx] = make_int4(s, d, e, 0);
                    atomicOr(&Mout[s >> 5], 1u << (s & 31));
                }
            }
            grid.sync();
        }
    }

    // ---- P4: compact active set S0 ----
    for (int w = tid; w < MASKW; w += NT) {
        unsigned bits = M0[w];
        while (bits) {
            int b = __ffs(bits) - 1;
            bits &= bits - 1;
            int node = w * 32 + b;
            int loc = atomicAdd(counters + 3, 1);
            if (loc < MAXLOC) { n2l[node] = loc; l2n[loc] = node; }
        }
    }
    grid.sync();

    int nloc = counters[3]; if (nloc > MAXLOC) nloc = MAXLOC;

    // ---- P5a: node init  x0 = nodes*valid, v0 = valid, meanv0 ----
    for (int loc = tid; loc < nloc; loc += NT) {
        int node = l2n[loc];
        float sum = 0.f;
        #pragma unroll 4
        for (int l = 0; l < LF; ++l) {
            float v = valid[node * LF + l];
            float x = nodes[node * LF + l] * v;
            X0[loc * LF + l] = x;
            VA[loc * LF + l] = v;
            sum += v;
        }
        MVA[loc] = sum * (1.0f / 48.0f);
    }
    // ---- P5b: per-edge loop-invariant scalar (one wave per edge, shuffle matvecs)
    //   w0 = gelu(relu(gelu(ea@W1+b1)@W2+b2)@Wg+bg)@Ww + bw ; remap src/dst -> local
    for (int j = wave; j < 3 * CAP_E; j += NWAVE) {
        int t = j >> 14;                 // / CAP_E
        int i = j & (CAP_E - 1);
        int c = counters[t]; if (c > CAP_E) c = CAP_E;
        if (i >= c) continue;
        int4 ent = lists[j];
        float ea_l = (lane < EDIMS) ? eattr[(long)ent.z * EDIMS + lane] : 0.f;
        float acc1 = (lane < 48) ? b1[lane] : 0.f;
        #pragma unroll
        for (int k = 0; k < EDIMS; ++k) {
            float eak = __shfl(ea_l, k, 64);
            if (lane < 48) acc1 += eak * W1[k * 48 + lane];
        }
        float h1 = (lane < 48) ? gelu_f(acc1) : 0.f;
        float acc2 = (lane < 48) ? b2[lane] : 0.f;
        #pragma unroll 8
        for (int k = 0; k < 48; ++k) {
            float hk = __shfl(h1, k, 64);
            if (lane < 48) acc2 += hk * W2[k * 48 + lane];
        }
        float h2 = fmaxf(acc2, 0.f);
        float acc3 = (lane < 48) ? bg[lane] : 0.f;
        #pragma unroll 8
        for (int k = 0; k < 48; ++k) {
            float hk = __shfl(h2, k, 64);
            if (lane < 48) acc3 += hk * Wg[k * 48 + lane];
        }
        float part = (lane < 48) ? gelu_f(acc3) * Ww[lane] : 0.f;
        #pragma unroll
        for (int o = 32; o > 0; o >>= 1) part += __shfl_down(part, o, 64);
        if (lane == 0) {
            float w0 = part + bw[0];
            int sl = n2l[ent.x]; if ((unsigned)sl >= (unsigned)MAXLOC) sl = 0;
            int dl = n2l[ent.y]; if ((unsigned)dl >= (unsigned)MAXLOC) dl = 0;
            lists[j] = make_int4(sl, dl, ent.z, __float_as_int(w0));
        }
    }
    grid.sync();

    const float wf0 = Wf[0], wf1 = Wf[1], wf2 = Wf[2], bfs = bf[0];

    // ---- 3 iterations: edge aggregate (atomics) -> node update (+agg re-zero) ----
    // rotation: it1: X0/VA/MVA -> XA/VB/MVB (edges E1=slot2, mask M1)
    //           it2: XA/VB/MVB -> XB/VA/MVA (edges E2=slot1, mask M2)
    //           it3: XB/VA/MVA -> out       (edges E3=slot0, mask M3={0})
    const int4*     eL[3] = { lists + 2 * CAP_E, lists + 1 * CAP_E, lists + 0 * CAP_E };
    const int*      eC[3] = { counters + 2, counters + 1, counters + 0 };
    const unsigned* Mt[3] = { M1, M2, M3 };
    const float*    Xp[3] = { X0, XA, XB };
    const float*    Vp[3] = { VA, VB, VA };
    const float*    MVp[3] = { MVA, MVB, MVA };
    float*          Xc[3] = { XA, XB, nullptr };
    float*          Vc[3] = { VB, VA, nullptr };
    float*          MVc[3] = { MVB, MVA, nullptr };

    for (int it = 0; it < 3; ++it) {
        const int4* list = eL[it];
        int c = *eC[it]; if (c > CAP_E) c = CAP_E;
        const float* Xprev = Xp[it];
        const float* MVprev = MVp[it];
        // edge aggregate: agg[dst] += sigmoid(meanv[src]*w0) * x_prev[src]
        for (int j = wave; j < c; j += NWAVE) {
            int4 ent = list[j];
            float s = sigm_f(MVprev[ent.x] * __int_as_float(ent.w));
            if (lane < 48)
                atomicAdd(&agg[ent.y * 48 + lane], s * Xprev[ent.x * 48 + lane]);
        }
        grid.sync();
        // node update for nodes in mask; always re-zero agg for next iteration
        const unsigned* M = Mt[it];
        const float* Vprev = Vp[it];
        bool last = (it == 2);
        for (int loc = tid; loc < nloc; loc += NT) {
            int node = l2n[loc];
            bool act = (M[node >> 5] & (1u << (node & 31))) != 0;
            float vsum = 0.f;
            for (int l = 0; l < LF; ++l) {
                float nh = agg[loc * LF + l];
                agg[loc * LF + l] = 0.f;
                if (!act) continue;
                float xo = Xprev[loc * LF + l];
                float vp = Vprev[loc * LF + l];
                float nv = 1.0f - vp;
                float m = sigm_f(nh * wf0 + xo * wf1 + nv * wf2 + bfs);
                float xn = (1.0f - m) * xo + nv * m * nh;
                if (last) {
                    out[l] = xn;           // only node 0 is active in M3
                } else {
                    float vn = ((X0[loc * LF + l] != xn) || (vp > 0.f)) ? 1.0f : 0.0f;
                    if (l == 0) vn = 0.0f;
                    Xc[it][loc * LF + l] = xn;
                    Vc[it][loc * LF + l] = vn;
                    vsum += vn;
                }
            }
            if (act && !last) MVc[it][loc] = vsum * (1.0f / 48.0f);
        }
        if (!last) grid.sync();
    }
}

extern "C" void kernel_launch(void* const* d_in, const int* in_sizes, int n_in,
                              void* d_out, int out_size, void* d_ws, size_t ws_size,
                              hipStream_t stream)
{
    const float* nodes = (const float*)d_in[0];
    const int*   eidx  = (const int*)d_in[1];     // (2,E) int32
    const float* eattr = (const float*)d_in[2];
    const float* valid = (const float*)d_in[3];
    // d_in[4]=r, d_in[5]=fx unused by reference
    const float* W1 = (const float*)d_in[6];
    const float* b1 = (const float*)d_in[7];
    const float* W2 = (const float*)d_in[8];
    const float* b2 = (const float*)d_in[9];
    const float* Wg = (const float*)d_in[10];
    const float* bg = (const float*)d_in[11];
    const float* Ww = (const float*)d_in[12];
    const float* bw = (const float*)d_in[13];
    const float* Wf = (const float*)d_in[14];
    const float* bf = (const float*)d_in[15];
    const int* src = eidx;
    const int* dst = eidx + NE;
    char* ws = (char*)d_ws;
    float* out = (float*)d_out;

    // ~15.6 MB workspace required
    if (ws_size < (size_t)16 * 1024 * 1024) return;

    void* args[] = {
        (void*)&nodes, (void*)&src, (void*)&dst, (void*)&eattr, (void*)&valid,
        (void*)&W1, (void*)&b1, (void*)&W2, (void*)&b2,
        (void*)&Wg, (void*)&bg, (void*)&Ww, (void*)&bw,
        (void*)&Wf, (void*)&bf, (void*)&ws, (void*)&out
    };
    hipLaunchCooperativeKernel((void*)fused_gat, dim3(NBLK), dim3(NTHR), args, 0, stream);
}

// Round 3
// 528.716 us; speedup vs baseline: 1.3851x; 1.3851x over previous
//
#include <hip/hip_runtime.h>
#include <math.h>

// Problem constants (from reference)
#define NN 100000          // nodes
#define LF 48              // features per node
#define NE 1600000         // edges
#define EDIMS 17           // edge_attr dim
#define MASKW 3125         // NN/32 bitmask words
#define CAP_E 16384        // per-level edge-list capacity (expected ~5k max level)
#define MAXLOC 12288       // active-node capacity (expected ~4.9k)
#define NBLK 256           // 1 block/CU, cooperative co-residency
#define NTHR 256
#define NT (NBLK * NTHR)
#define NWAVE (NT / 64)    // 1024

static_assert(NN == MASKW * 32, "mask width");
static_assert((CAP_E & (CAP_E - 1)) == 0, "CAP_E pow2");
static_assert((NWAVE & (NWAVE - 1)) == 0, "NWAVE pow2");

__device__ __forceinline__ float gelu_f(float x) {
    return 0.5f * x * (1.0f + erff(x * 0.7071067811865475f));
}
__device__ __forceinline__ float sigm_f(float x) {
    return 1.0f / (1.0f + expf(-x));
}

// Hand-rolled sense-counting grid barrier, agent scope.
// arrive/gen pre-zeroed by hipMemsetAsync before launch. Spin is RELAXED
// (no repeated cache-inv); one ACQUIRE load on exit publishes peers' writes.
__device__ __forceinline__ void gbar(int* arrive, int* gen, int& mygen) {
    __syncthreads();
    if (threadIdx.x == 0) {
        int g = ++mygen;
        int t = __hip_atomic_fetch_add(arrive, 1, __ATOMIC_ACQ_REL, __HIP_MEMORY_SCOPE_AGENT);
        if (t == NBLK - 1) {
            __hip_atomic_store(arrive, 0, __ATOMIC_RELAXED, __HIP_MEMORY_SCOPE_AGENT);
            __hip_atomic_store(gen, g, __ATOMIC_RELEASE, __HIP_MEMORY_SCOPE_AGENT);
        } else {
            while (__hip_atomic_load(gen, __ATOMIC_RELAXED, __HIP_MEMORY_SCOPE_AGENT) < g)
                __builtin_amdgcn_s_sleep(1);
            (void)__hip_atomic_load(gen, __ATOMIC_ACQUIRE, __HIP_MEMORY_SCOPE_AGENT);
        }
    }
    __syncthreads();
}

__global__ __launch_bounds__(NTHR) void fused_gat(
    const float* __restrict__ nodes, const int* __restrict__ src, const int* __restrict__ dst,
    const float* __restrict__ eattr, const float* __restrict__ valid,
    const float* __restrict__ W1, const float* __restrict__ b1,
    const float* __restrict__ W2, const float* __restrict__ b2,
    const float* __restrict__ Wg, const float* __restrict__ bg,
    const float* __restrict__ Ww, const float* __restrict__ bw,
    const float* __restrict__ Wf, const float* __restrict__ bf,
    char* ws, float* __restrict__ out)
{
    const int tid  = blockIdx.x * NTHR + threadIdx.x;
    const int wave = tid >> 6;
    const int lane = tid & 63;
    int mygen = 0;

    // ---- workspace carve ----
    size_t off = 0;
    auto carve = [&](size_t bytes) -> char* {
        char* p = ws + off;
        off += (bytes + 255) & ~(size_t)255;
        return p;
    };
    int*      ctrl = (int*)carve(4096);                // memset-zeroed host-side
    int*      arrive = ctrl;                           // [0]
    int*      gen = ctrl + 32;                         // separate cacheline
    int*      cnt = ctrl + 64;                         // [0..2]=|E3|,|E2|,|E1|  [3]=nloc
    unsigned* M3 = (unsigned*)carve(MASKW * 4);
    unsigned* M2 = (unsigned*)carve(MASKW * 4);
    unsigned* M1 = (unsigned*)carve(MASKW * 4);
    unsigned* M0 = (unsigned*)carve(MASKW * 4);
    int*      n2l = (int*)carve((size_t)NN * 4);
    int*      l2n = (int*)carve((size_t)MAXLOC * 4);
    int4*     lists = (int4*)carve((size_t)3 * CAP_E * 16); // slot0=E3, slot1=E2, slot2=E1
    float*    X0 = (float*)carve((size_t)MAXLOC * LF * 4);
    float*    XA = (float*)carve((size_t)MAXLOC * LF * 4);
    float*    XB = (float*)carve((size_t)MAXLOC * LF * 4);
    float*    VA = (float*)carve((size_t)MAXLOC * LF * 4);
    float*    VB = (float*)carve((size_t)MAXLOC * LF * 4);
    float*    MVA = (float*)carve((size_t)MAXLOC * 4);
    float*    MVB = (float*)carve((size_t)MAXLOC * 4);
    float*    agg = (float*)carve((size_t)MAXLOC * LF * 4);

    // ---- P0: zero masks + agg, seed node 0 (loc 0) ----
    for (int i = tid; i < MASKW; i += NT) { M3[i] = 0u; M2[i] = 0u; M1[i] = 0u; M0[i] = 0u; }
    for (int i = tid; i < MAXLOC * LF; i += NT) agg[i] = 0.f;
    if (tid == 0) {
        M3[0] = 1u; M2[0] = 1u; M1[0] = 1u; M0[0] = 1u;
        n2l[0] = 0; l2n[0] = 0; cnt[3] = 1;            // node 0 pre-assigned
    }
    gbar(arrive, gen, mygen);                          // barrier 1

    // ---- BFS levels (3 scans). First-touch loc assignment for new src nodes.
    // Invariant: Min == set of all nodes assigned so far; n2l stable for Min.
    {
        const unsigned* Mins[3]  = { M3, M2, M1 };
        unsigned*       Mouts[3] = { M2, M1, M0 };
        const int4* dst4 = (const int4*)dst;
        for (int lvl = 0; lvl < 3; ++lvl) {
            const unsigned* Min = Mins[lvl];
            unsigned* Mout = Mouts[lvl];
            int4* list = lists + lvl * CAP_E;
            int* c = cnt + lvl;
            // Mout |= Min (these nodes already have locs)
            for (int w = tid; w < MASKW; w += NT) {
                unsigned m = Min[w];
                if (m) atomicOr(&Mout[w], m);
            }
            for (int e4 = tid; e4 < NE / 4; e4 += NT) {
                int4 d4 = dst4[e4];
                int ds_[4] = { d4.x, d4.y, d4.z, d4.w };
                #pragma unroll
                for (int q = 0; q < 4; ++q) {
                    int d = ds_[q];
                    if (Min[d >> 5] & (1u << (d & 31))) {
                        int e = e4 * 4 + q;
                        int s = src[e];
                        int idx = atomicAdd(c, 1);
                        int dloc = n2l[d];               // stable (d in Min)
                        if (idx < CAP_E) list[idx] = make_int4(s, dloc, e, 0);
                        unsigned sb = 1u << (s & 31);
                        if (!(Min[s >> 5] & sb)) {       // s not yet assigned
                            unsigned old = atomicOr(&Mout[s >> 5], sb);
                            if (!(old & sb)) {           // this thread first-touches s
                                int loc = atomicAdd(cnt + 3, 1);
                                if (loc < MAXLOC) { n2l[s] = loc; l2n[loc] = s; }
                            }
                        }
                    }
                }
            }
            gbar(arrive, gen, mygen);                    // barriers 2,3,4
        }
    }

    int nloc = cnt[3]; if (nloc > MAXLOC) nloc = MAXLOC;

    // ---- P4a: node init (wave per node) ----
    for (int loc = wave; loc < nloc; loc += NWAVE) {
        int node = l2n[loc];
        float v = 0.f;
        if (lane < LF) {
            v = valid[node * LF + lane];
            float x = nodes[node * LF + lane] * v;
            X0[loc * LF + lane] = x;
            VA[loc * LF + lane] = v;
        }
        float sv = v;
        #pragma unroll
        for (int o = 32; o > 0; o >>= 1) sv += __shfl_down(sv, o, 64);
        if (lane == 0) MVA[loc] = sv * (1.0f / 48.0f);
    }
    // ---- P4b: per-edge loop-invariant gate scalar w0 (wave per edge) ----
    //   w0 = gelu(relu(gelu(ea@W1+b1)@W2+b2)@Wg+bg)@Ww + bw ; remap src -> loc
    for (int j = wave; j < 3 * CAP_E; j += NWAVE) {
        int t = j >> 14;
        int i = j & (CAP_E - 1);
        int c = cnt[t]; if (c > CAP_E) c = CAP_E;
        if (i >= c) continue;
        int4 ent = lists[j];                             // (s_global, dloc, e, 0)
        float ea_l = (lane < EDIMS) ? eattr[(long)ent.z * EDIMS + lane] : 0.f;
        float acc1 = (lane < 48) ? b1[lane] : 0.f;
        #pragma unroll
        for (int k = 0; k < EDIMS; ++k) {
            float eak = __shfl(ea_l, k, 64);
            if (lane < 48) acc1 += eak * W1[k * 48 + lane];
        }
        float h1 = (lane < 48) ? gelu_f(acc1) : 0.f;
        float acc2 = (lane < 48) ? b2[lane] : 0.f;
        #pragma unroll 8
        for (int k = 0; k < 48; ++k) {
            float hk = __shfl(h1, k, 64);
            if (lane < 48) acc2 += hk * W2[k * 48 + lane];
        }
        float h2 = fmaxf(acc2, 0.f);
        float acc3 = (lane < 48) ? bg[lane] : 0.f;
        #pragma unroll 8
        for (int k = 0; k < 48; ++k) {
            float hk = __shfl(h2, k, 64);
            if (lane < 48) acc3 += hk * Wg[k * 48 + lane];
        }
        float part = (lane < 48) ? gelu_f(acc3) * Ww[lane] : 0.f;
        #pragma unroll
        for (int o = 32; o > 0; o >>= 1) part += __shfl_down(part, o, 64);
        if (lane == 0) {
            float w0 = part + bw[0];
            int sl = n2l[ent.x]; if ((unsigned)sl >= (unsigned)MAXLOC) sl = 0;
            lists[j] = make_int4(sl, ent.y, __float_as_int(w0), 0);
        }
    }
    gbar(arrive, gen, mygen);                            // barrier 5

    const float wf0 = Wf[0], wf1 = Wf[1], wf2 = Wf[2], bfc = bf[0];

    // ---- 3 iterations, dst-ownership (wave = dloc & 1023): scatter + update, NO
    // barrier between them (a wave updates only dsts it exclusively accumulated).
    // it0: X0/VA/MVA -> XA/VB/MVB (E1=slot2, M1); it1: XA/VB/MVB -> XB/VA/MVA
    // (E2=slot1, M2); it2: XB/VA/MVA -> out (E3=slot0, M3={0}).
    const int4*     eL[3] = { lists + 2 * CAP_E, lists + 1 * CAP_E, lists + 0 * CAP_E };
    const int       eC[3] = { 2, 1, 0 };
    const unsigned* Mt[3] = { M1, M2, M3 };
    const float*    Xp[3] = { X0, XA, XB };
    const float*    Vp[3] = { VA, VB, VA };
    const float*    MVp[3] = { MVA, MVB, MVA };
    float*          Xc[3] = { XA, XB, nullptr };
    float*          Vc[3] = { VB, VA, nullptr };
    float*          MVc[3] = { MVB, MVA, nullptr };

    for (int it = 0; it < 3; ++it) {
        const int4* list = eL[it];
        int c = cnt[eC[it]]; if (c > CAP_E) c = CAP_E;
        const float* Xprev = Xp[it];
        const float* MVprev = MVp[it];
        // scatter: coalesced scan, ballot-extract owned edges, exclusive accumulate
        for (int base = 0; base < c; base += 64) {
            int4 ent = make_int4(0, 0, 0, 0);
            bool own = false;
            int j = base + lane;
            if (j < c) {
                ent = list[j];
                own = ((ent.y & (NWAVE - 1)) == wave);
            }
            unsigned long long sel = __ballot(own);
            while (sel) {
                int b = __ffsll(sel) - 1;
                sel &= sel - 1;
                int sloc  = __shfl(ent.x, b, 64);
                int dloc  = __shfl(ent.y, b, 64);
                float w0  = __shfl(__int_as_float(ent.z), b, 64);
                float sg = sigm_f(MVprev[sloc] * w0);
                if (lane < LF)
                    agg[dloc * LF + lane] += sg * Xprev[sloc * LF + lane];
            }
        }
        // update owned nodes in mask; re-zero agg for next iteration
        const unsigned* M = Mt[it];
        const float* Vprev = Vp[it];
        bool last = (it == 2);
        for (int loc = wave; loc < nloc; loc += NWAVE) {
            int node = l2n[loc];
            if (!(M[node >> 5] & (1u << (node & 31)))) continue;
            float vn = 0.f;
            if (lane < LF) {
                float nh = agg[loc * LF + lane];
                agg[loc * LF + lane] = 0.f;
                float xo = Xprev[loc * LF + lane];
                float vp = Vprev[loc * LF + lane];
                float nv = 1.0f - vp;
                float m = sigm_f(nh * wf0 + xo * wf1 + nv * wf2 + bfc);
                float xn = (1.0f - m) * xo + nv * m * nh;
                if (last) {
                    out[lane] = xn;                      // only node 0 active in M3
                } else {
                    vn = ((X0[loc * LF + lane] != xn) || (vp > 0.f)) ? 1.0f : 0.0f;
                    if (lane == 0) vn = 0.0f;
                    Xc[it][loc * LF + lane] = xn;
                    Vc[it][loc * LF + lane] = vn;
                }
            }
            if (!last) {
                float sv = vn;
                #pragma unroll
                for (int o = 32; o > 0; o >>= 1) sv += __shfl_down(sv, o, 64);
                if (lane == 0) MVc[it][loc] = sv * (1.0f / 48.0f);
            }
        }
        if (!last) gbar(arrive, gen, mygen);             // barriers 6,7
    }
}

extern "C" void kernel_launch(void* const* d_in, const int* in_sizes, int n_in,
                              void* d_out, int out_size, void* d_ws, size_t ws_size,
                              hipStream_t stream)
{
    const float* nodes = (const float*)d_in[0];
    const int*   eidx  = (const int*)d_in[1];     // (2,E) int32
    const float* eattr = (const float*)d_in[2];
    const float* valid = (const float*)d_in[3];
    const float* W1 = (const float*)d_in[6];
    const float* b1 = (const float*)d_in[7];
    const float* W2 = (const float*)d_in[8];
    const float* b2 = (const float*)d_in[9];
    const float* Wg = (const float*)d_in[10];
    const float* bg = (const float*)d_in[11];
    const float* Ww = (const float*)d_in[12];
    const float* bw = (const float*)d_in[13];
    const float* Wf = (const float*)d_in[14];
    const float* bf = (const float*)d_in[15];
    const int* src = eidx;
    const int* dst = eidx + NE;
    char* ws = (char*)d_ws;
    float* out = (float*)d_out;

    if (ws_size < (size_t)16 * 1024 * 1024) return;  // ~15.5 MB needed

    // barrier/counter block must be zero before the cooperative kernel runs
    hipMemsetAsync(ws, 0, 4096, stream);

    void* args[] = {
        (void*)&nodes, (void*)&src, (void*)&dst, (void*)&eattr, (void*)&valid,
        (void*)&W1, (void*)&b1, (void*)&W2, (void*)&b2,
        (void*)&Wg, (void*)&bg, (void*)&Ww, (void*)&bw,
        (void*)&Wf, (void*)&bf, (void*)&ws, (void*)&out
    };
    hipLaunchCooperativeKernel((void*)fused_gat, dim3(NBLK), dim3(NTHR), args, 0, stream);
}